// Round 2
// baseline (901.444 us; speedup 1.0000x reference)
//
#include <hip/hip_runtime.h>

#define BROWS 131072

typedef __attribute__((ext_vector_type(8))) __bf16 bf16x8;
typedef __attribute__((ext_vector_type(4))) float f32x4;

__device__ __forceinline__ float sigmoidf_(float x) {
    return 1.0f / (1.0f + __expf(-x));
}
__device__ __forceinline__ float tanhf_(float x) {
    return 1.0f - 2.0f / (__expf(2.0f * x) + 1.0f);
}

// ---------------------------------------------------------------------------
// Kernel 1: transpose W_gates rows 3..258 (h part) into bf16 WT[1024][256].
// Thread owns (c, k8..k8+7) -> one 16B bf16x8 store. Wg is 1MB, L2-resident.
// ---------------------------------------------------------------------------
__global__ __launch_bounds__(256)
void wt_kernel(const float* __restrict__ Wg, __bf16* __restrict__ WT) {
    int gid = blockIdx.x * 256 + threadIdx.x;    // 0..32767
    int c = gid >> 5;                            // 0..1023
    int k8 = (gid & 31) * 8;                     // 0..248
    bf16x8 v;
#pragma unroll
    for (int j = 0; j < 8; ++j)
        v[j] = (__bf16)Wg[(3 + k8 + j) * 1024 + c];
    *(bf16x8*)(WT + c * 256 + k8) = v;           // 16B coalesced store
}

// ---------------------------------------------------------------------------
// Kernel 2: switch counts, v2. Thread-per-row; the c-loop is WAVE-UNIFORM so
// W_switch loads compile to scalar (SGPR) loads - no LDS, no barriers, no
// cross-lane ops until the final ballot. Each thread streams its own row as
// float4; every 64B line is fully consumed within 4 iterations.
// sigmoid(s) > 0.5  <=>  s > 0.
// ---------------------------------------------------------------------------
__global__ __launch_bounds__(256)
void switch_kernel(const float* __restrict__ x, const float* __restrict__ h,
                   const float* __restrict__ Wsw, const float* __restrict__ bsw,
                   int* __restrict__ cnt) {
    const int row = blockIdx.x * 256 + threadIdx.x;
    const float* hr = h + (size_t)row * 256;

    const float x0 = x[row * 3 + 0];
    const float x1 = x[row * 3 + 1];
    const float x2 = x[row * 3 + 2];
    float si = x0 * Wsw[0] + x1 * Wsw[2] + x2 * Wsw[4] + bsw[0];
    float sg = x0 * Wsw[1] + x1 * Wsw[3] + x2 * Wsw[5] + bsw[1];

#pragma unroll 8
    for (int c4 = 0; c4 < 64; ++c4) {
        float4 v = *(const float4*)(hr + c4 * 4);
        float2 wa = *(const float2*)&Wsw[(3 + c4 * 4 + 0) * 2];  // uniform -> s_load
        float2 wb = *(const float2*)&Wsw[(3 + c4 * 4 + 1) * 2];
        float2 wc = *(const float2*)&Wsw[(3 + c4 * 4 + 2) * 2];
        float2 wd = *(const float2*)&Wsw[(3 + c4 * 4 + 3) * 2];
        si += v.x * wa.x + v.y * wb.x + v.z * wc.x + v.w * wd.x;
        sg += v.x * wa.y + v.y * wb.y + v.z * wc.y + v.w * wd.y;
    }

    unsigned long long bi = __ballot(si > 0.0f);
    unsigned long long bg = __ballot(sg > 0.0f);
    if ((threadIdx.x & 63) == 0) {
        atomicAdd(&cnt[0], (int)__popcll(bi));
        atomicAdd(&cnt[1], (int)__popcll(bg));
    }
}

// ---------------------------------------------------------------------------
// Kernel 3: main GEMM + LSTM epilogue, v2: NO LDS, NO barriers.
// A-fragments for mfma_f32_16x16x32_bf16 are lane ln = row, k = q*8..q*8+7 --
// 8 CONTIGUOUS elements of row-major h. Load them straight from global as
// 2x float4 and convert to bf16 in-register. B-fragments load from WT as
// before. Per K-chunk: 12 VMEM + cvt + 16 MFMA, zero synchronization.
// XCD-chunked bijective swizzle keeps the 8 j0-siblings of each m-tile
// adjacent on one XCD (round-1 proved this holds FETCH at ~141 MB).
// ---------------------------------------------------------------------------
__global__ __launch_bounds__(256)
void lstm_main(const float* __restrict__ x,      // B x 3
               const float* __restrict__ h,      // B x 256
               const float* __restrict__ c_cur,  // B x 256
               const float* __restrict__ Wg,     // 259 x 1024 (fp32)
               const float* __restrict__ bg,     // 1024
               const __bf16* __restrict__ WT,    // 1024 x 256 bf16 (B^T)
               const int* __restrict__ cnt,
               float* __restrict__ out) {
    const int tid = threadIdx.x;
    const int lane = tid & 63;
    const int w = tid >> 6;
    const int q = lane >> 4;
    const int ln = lane & 15;

    // XCD-chunked swizzle: bid -> (m-tile, j0-block)
    const int bid = blockIdx.x;                  // 0..8191
    const int jseq = bid >> 3;                   // 0..1023 per-XCD sequence
    const int m0 = (((bid & 7) << 7) + (jseq >> 3)) << 7;  // m-tile * 128
    const int j0 = (jseq & 7) << 5;              // h-col block * 32

    const int wrow = (w >> 1) * 64;
    const int colh = j0 + (w & 1) * 16 + ln;     // h column 0..255

    const int ci = cnt[0], cg = cnt[1];          // thr = B*0.5 = 65536 exactly
    const bool cond_i = (cg < 65536) && (ci > 65536);
    const bool cond_g = (cg > 65536) && (ci < 65536);

    // ---- accumulator init: bias + input @ W_gates[0:3] ----
    f32x4 acc[4][4];
    float bcol[4], wx0[4], wx1[4], wx2[4];
#pragma unroll
    for (int nt = 0; nt < 4; ++nt) {
        int colg = nt * 256 + colh;
        bcol[nt] = bg[colg];
        wx0[nt] = Wg[0 * 1024 + colg];
        wx1[nt] = Wg[1 * 1024 + colg];
        wx2[nt] = Wg[2 * 1024 + colg];
    }
#pragma unroll
    for (int mt = 0; mt < 4; ++mt) {
#pragma unroll
        for (int r = 0; r < 4; ++r) {
            int row = m0 + wrow + mt * 16 + q * 4 + r;
            float x0 = x[row * 3 + 0];
            float x1 = x[row * 3 + 1];
            float x2 = x[row * 3 + 2];
#pragma unroll
            for (int nt = 0; nt < 4; ++nt) {
                acc[mt][nt][r] = bcol[nt] + x0 * wx0[nt] + x1 * wx1[nt] + x2 * wx2[nt];
            }
        }
    }

    // ---- per-lane A/B fragment base pointers ----
    const float* habase[4];
#pragma unroll
    for (int mt = 0; mt < 4; ++mt)
        habase[mt] = h + (size_t)(m0 + wrow + mt * 16 + ln) * 256 + q * 8;

    const __bf16* wtb[4];
#pragma unroll
    for (int nt = 0; nt < 4; ++nt)
        wtb[nt] = WT + (nt * 256 + colh) * 256 + q * 8;

    // ---- K loop: 8 chunks of K=32, A direct from global (fp32 -> bf16) ----
#pragma unroll 4
    for (int kc = 0; kc < 8; ++kc) {
        bf16x8 afrag[4];
#pragma unroll
        for (int mt = 0; mt < 4; ++mt) {
            float4 a0 = *(const float4*)(habase[mt] + kc * 32);
            float4 a1 = *(const float4*)(habase[mt] + kc * 32 + 4);
            bf16x8 v;
            v[0] = (__bf16)a0.x; v[1] = (__bf16)a0.y;
            v[2] = (__bf16)a0.z; v[3] = (__bf16)a0.w;
            v[4] = (__bf16)a1.x; v[5] = (__bf16)a1.y;
            v[6] = (__bf16)a1.z; v[7] = (__bf16)a1.w;
            afrag[mt] = v;
        }
        bf16x8 bfrag[4];
#pragma unroll
        for (int nt = 0; nt < 4; ++nt)
            bfrag[nt] = *(const bf16x8*)(wtb[nt] + kc * 32);
#pragma unroll
        for (int mt = 0; mt < 4; ++mt)
#pragma unroll
            for (int nt = 0; nt < 4; ++nt)
                acc[mt][nt] = __builtin_amdgcn_mfma_f32_16x16x32_bf16(
                    afrag[mt], bfrag[nt], acc[mt][nt], 0, 0, 0);
    }

    // ---- epilogue: per lane, acc[mt][nt][r] = gate nt at (row, colh) ----
#pragma unroll
    for (int mt = 0; mt < 4; ++mt) {
#pragma unroll
        for (int r = 0; r < 4; ++r) {
            int row = m0 + wrow + mt * 16 + q * 4 + r;
            float gi = sigmoidf_(acc[mt][0][r]);
            float gf = sigmoidf_(acc[mt][1][r]);
            float gg = tanhf_(acc[mt][2][r]);
            float go = sigmoidf_(acc[mt][3][r]);
            float c = c_cur[row * 256 + colh];
            float X = cond_i ? gi : (cond_g ? gg : gi * gg);
            float cn = gf * c + X;
            float hn = go * tanhf_(cn);
            out[row * 256 + colh] = hn;
            out[BROWS * 256 + row * 256 + colh] = cn;
        }
    }
}

// ---------------------------------------------------------------------------
extern "C" void kernel_launch(void* const* d_in, const int* in_sizes, int n_in,
                              void* d_out, int out_size, void* d_ws, size_t ws_size,
                              hipStream_t stream) {
    const float* x   = (const float*)d_in[0];   // input_tensor B x 3
    const float* h   = (const float*)d_in[1];   // h_cur B x 256
    const float* c   = (const float*)d_in[2];   // c_cur B x 256
    const float* Wg  = (const float*)d_in[3];   // W_gates 259 x 1024
    const float* bg  = (const float*)d_in[4];   // b_gates 1024
    const float* Wsw = (const float*)d_in[5];   // W_switch 259 x 2
    const float* bsw = (const float*)d_in[6];   // b_switch 2
    float* out = (float*)d_out;

    int* cnt = (int*)d_ws;
    __bf16* WT = (__bf16*)((char*)d_ws + 1024);  // 1024*256*2 = 512 KB

    hipMemsetAsync(d_ws, 0, 8, stream);
    wt_kernel<<<128, 256, 0, stream>>>(Wg, WT);
    switch_kernel<<<512, 256, 0, stream>>>(x, h, Wsw, bsw, cnt);
    lstm_main<<<8192, 256, 0, stream>>>(x, h, c, Wg, bg, WT, cnt, out);
}